// Round 1
// baseline (923.632 us; speedup 1.0000x reference)
//
#include <hip/hip_runtime.h>
#include <hip/hip_bf16.h>
#include <cstdint>
#include <cstddef>

#define B_ 2
#define S_ 2048
#define E_ 4096
#define H_ 32
#define KVH_ 8
#define D_ 128
#define M_ (B_*S_)      // 4096 rows (B*S)
#define HD_ (H_*D_)     // 4096
#define KVD_ (KVH_*D_)  // 1024

typedef unsigned short u16;
typedef __attribute__((ext_vector_type(8))) short bf16x8;
typedef __attribute__((ext_vector_type(4))) float f32x4;

__device__ __forceinline__ float bf2f(u16 u) {
  union { float f; uint32_t i; } v; v.i = ((uint32_t)u) << 16; return v.f;
}
__device__ __forceinline__ u16 f2bf(float f) {
  union { float f; uint32_t i; } v; v.f = f;
  uint32_t r = v.i + 0x7FFF + ((v.i >> 16) & 1);   // RNE
  return (u16)(r >> 16);
}

// async global->LDS, 16B per lane; LDS dest = wave-uniform base + lane*16
__device__ __forceinline__ void gload_lds16(const void* g, void* l) {
  __builtin_amdgcn_global_load_lds(
      (const __attribute__((address_space(1))) void*)g,
      (__attribute__((address_space(3))) void*)l, 16, 0, 0);
}

// ---------------- elementwise f32 -> bf16 ----------------
__global__ __launch_bounds__(256) void k_f2bf(const float* __restrict__ in,
                                              u16* __restrict__ out, int n) {
  int i = (blockIdx.x * 256 + threadIdx.x) * 4;
  if (i + 3 < n) {
    float4 v = *(const float4*)(in + i);
    *(ushort4*)(out + i) = make_ushort4(f2bf(v.x), f2bf(v.y), f2bf(v.z), f2bf(v.w));
  }
}

// ---------------- transpose-convert f32 [R][C] -> bf16 [C][R] ----------------
__global__ __launch_bounds__(256) void k_transpose_f2bf(const float* __restrict__ in,
                                                        u16* __restrict__ out, int R, int C) {
  __shared__ float tile[32][33];
  int c0 = blockIdx.x * 32, r0 = blockIdx.y * 32;
  int lx = threadIdx.x, ly = threadIdx.y;
#pragma unroll
  for (int yy = 0; yy < 32; yy += 8)
    tile[ly + yy][lx] = in[(size_t)(r0 + ly + yy) * C + c0 + lx];
  __syncthreads();
#pragma unroll
  for (int yy = 0; yy < 32; yy += 8)
    out[(size_t)(c0 + ly + yy) * R + r0 + lx] = f2bf(tile[lx][ly + yy]);
}

// ---------------- transpose v_lin [B*S][KVD] -> vt [B][KVH][D][S] (bf16) -------
__global__ __launch_bounds__(256) void k_transpose_v(const u16* __restrict__ vlin,
                                                     u16* __restrict__ vt) {
  __shared__ u16 tile[32][33];
  int bk = blockIdx.z;             // b*KVH + kvh
  int b = bk >> 3, kvh = bk & 7;
  int s0 = blockIdx.x * 32, d0 = blockIdx.y * 32;
  int lx = threadIdx.x, ly = threadIdx.y;
#pragma unroll
  for (int yy = 0; yy < 32; yy += 8)
    tile[ly + yy][lx] = vlin[(size_t)(b * S_ + s0 + ly + yy) * KVD_ + kvh * D_ + d0 + lx];
  __syncthreads();
#pragma unroll
  for (int yy = 0; yy < 32; yy += 8)
    vt[((size_t)bk * D_ + d0 + ly + yy) * S_ + s0 + lx] = tile[lx][ly + yy];
}

// ---------------- RoPE sin/cos table [S][64] ----------------
__global__ __launch_bounds__(256) void k_table(float2* __restrict__ tab) {
  int i = blockIdx.x * 256 + threadIdx.x;
  if (i < S_ * 64) {
    int s = i >> 6, d = i & 63;
    float inv = powf(10000.0f, -(float)d / 64.0f);
    float f = (float)s * inv;
    tab[i] = make_float2(sinf(f), cosf(f));
  }
}

// ---------------- RoPE + head reorder: [B,S,heads*D] -> [B,heads,S,D] ----------
__global__ __launch_bounds__(256) void k_rope(const u16* __restrict__ in, u16* __restrict__ out,
                                              const float2* __restrict__ tab,
                                              const int* __restrict__ pos,
                                              int heads, int total) {
  int i = blockIdx.x * 256 + threadIdx.x;
  if (i >= total) return;
  int d = i & 63;
  int s = (i >> 6) & (S_ - 1);
  int bh = i >> 17;                 // 64*S_ = 2^17
  int h = bh % heads, b = bh / heads;
  size_t ibase = ((size_t)(b * S_ + s)) * (heads * D_) + h * D_;
  float2 scv = tab[pos[b * S_ + s] * 64 + d];
  float x1 = bf2f(in[ibase + d]), x2 = bf2f(in[ibase + d + 64]);
  size_t obase = ((size_t)bh * S_ + s) * D_;
  out[obase + d]      = f2bf(x1 * scv.y - x2 * scv.x);
  out[obase + d + 64] = f2bf(x2 * scv.y + x1 * scv.x);
}

// ---------------- bf16 GEMM: C[M,N] = A[M,K] * BT[N,K]^T ----------------
// 128x128 tile, BK=64, 4 waves (2x2), swizzled LDS via pre-swizzled global src.
template<bool OUTF32>
__global__ __launch_bounds__(256) void k_gemm_bt(const u16* __restrict__ A,
                                                 const u16* __restrict__ BT,
                                                 void* __restrict__ Cp,
                                                 int M, int N, int K) {
  __shared__ __align__(16) u16 As[128 * 64];
  __shared__ __align__(16) u16 Bs[128 * 64];
  const int tid = threadIdx.x;
  const int wid = tid >> 6, lane = tid & 63;
  const int lrow = lane & 15, lk = lane >> 4;
  const int nbn = N >> 7;
  const int tm = blockIdx.x / nbn, tn = blockIdx.x % nbn;
  const int m0 = tm << 7, n0 = tn << 7;
  const int wr = wid >> 1, wc = wid & 1;

  f32x4 acc[4][4] = {};
  const int srow = (wid << 3) + (lane >> 3);  // row within 32-row staging chunk
  const int sblk = lane & 7;

  for (int kt = 0; kt < K; kt += 64) {
#pragma unroll
    for (int c = 0; c < 4; ++c) {
      int r = (c << 5) + srow;
      int gb = sblk ^ (r & 7);   // pre-swizzle source so LDS reads are conflict-lite
      gload_lds16(A  + (size_t)(m0 + r) * K + kt + (gb << 3), As + (c << 11) + (wid << 9));
      gload_lds16(BT + (size_t)(n0 + r) * K + kt + (gb << 3), Bs + (c << 11) + (wid << 9));
    }
    __syncthreads();
    bf16x8 af[4][2], bfr[4][2];
#pragma unroll
    for (int x = 0; x < 4; ++x) {
#pragma unroll
      for (int ks = 0; ks < 2; ++ks) {
        int ar = (wr << 6) + (x << 4) + lrow;
        af[x][ks]  = *(const bf16x8*)(As + ar * 64 + ((((ks << 2) + lk) ^ (ar & 7)) << 3));
        int br = (wc << 6) + (x << 4) + lrow;
        bfr[x][ks] = *(const bf16x8*)(Bs + br * 64 + ((((ks << 2) + lk) ^ (br & 7)) << 3));
      }
    }
#pragma unroll
    for (int ks = 0; ks < 2; ++ks)
#pragma unroll
      for (int mi = 0; mi < 4; ++mi)
#pragma unroll
        for (int ni = 0; ni < 4; ++ni)
          acc[mi][ni] = __builtin_amdgcn_mfma_f32_16x16x32_bf16(af[mi][ks], bfr[ni][ks],
                                                                acc[mi][ni], 0, 0, 0);
    __syncthreads();
  }

#pragma unroll
  for (int mi = 0; mi < 4; ++mi)
#pragma unroll
    for (int ni = 0; ni < 4; ++ni) {
      int col = n0 + (wc << 6) + (ni << 4) + lrow;
#pragma unroll
      for (int j = 0; j < 4; ++j) {
        int row = m0 + (wr << 6) + (mi << 4) + (lk << 2) + j;
        if (OUTF32) ((float*)Cp)[(size_t)row * N + col] = acc[mi][ni][j];
        else        ((u16*)Cp)[(size_t)row * N + col]  = f2bf(acc[mi][ni][j]);
      }
    }
}

// ---------------- flash attention (causal, GQA) ----------------
// grid = B*H*(S/64); block = 256 (4 waves x 16 q-rows)
__global__ __launch_bounds__(256) void k_attn(const u16* __restrict__ Q,
                                              const u16* __restrict__ Kr,
                                              const u16* __restrict__ Vt,
                                              u16* __restrict__ ctx) {
  __shared__ __align__(16) u16 Ks[64 * 128];
  __shared__ __align__(16) u16 Vs[128 * 64];
  __shared__ __align__(16) u16 Ps[4][16 * 72];
  const int bid = blockIdx.x;
  const int qt = bid & 31;
  const int h  = (bid >> 5) & 31;
  const int b  = bid >> 10;
  const int kvh = h >> 2;
  const int tid = threadIdx.x;
  const int wid = tid >> 6, lane = tid & 63;
  const int lrow = lane & 15, lk = lane >> 4;

  // Q fragments in registers (16 rows per wave, D=128 -> 4 k-steps)
  const u16* qbase = Q + (((size_t)(b * H_ + h) * S_) + qt * 64 + wid * 16) * D_;
  bf16x8 qf[4];
#pragma unroll
  for (int ks = 0; ks < 4; ++ks)
    qf[ks] = *(const bf16x8*)(qbase + lrow * D_ + ks * 32 + lk * 8);

  float m[4] = {-1e30f, -1e30f, -1e30f, -1e30f};
  float l[4] = {0.f, 0.f, 0.f, 0.f};
  f32x4 o[8] = {};

  const u16* kbase = Kr + (size_t)(b * KVH_ + kvh) * S_ * D_;
  const u16* vbase = Vt + (size_t)(b * KVH_ + kvh) * D_ * S_;
  const float scale = 0.088388347648318447f;  // 1/sqrt(128)

  for (int kb = 0; kb <= qt; ++kb) {
    const int kv0 = kb << 6;
    // stage K tile [64][128], swizzled source
#pragma unroll
    for (int c = 0; c < 4; ++c) {
      int r = (c << 4) + (wid << 2) + lk;
      int gb = lrow ^ (r & 7);
      gload_lds16(kbase + (size_t)(kv0 + r) * D_ + (gb << 3), Ks + (c << 11) + (wid << 9));
    }
    // stage V^T tile [128][64], swizzled source
#pragma unroll
    for (int c = 0; c < 4; ++c) {
      int r = (c << 5) + (wid << 3) + (lane >> 3);
      int gb = (lane & 7) ^ (r & 7);
      gload_lds16(vbase + (size_t)r * S_ + kv0 + (gb << 3), Vs + (c << 11) + (wid << 9));
    }
    __syncthreads();

    // S = Q K^T (16 MFMAs)
    f32x4 sc[4] = {};
#pragma unroll
    for (int n0 = 0; n0 < 4; ++n0) {
#pragma unroll
      for (int ks = 0; ks < 4; ++ks) {
        int krow = (n0 << 4) + lrow;
        bf16x8 kf = *(const bf16x8*)(Ks + krow * 128 + ((((ks << 2) + lk) ^ (krow & 7)) << 3));
        sc[n0] = __builtin_amdgcn_mfma_f32_16x16x32_bf16(qf[ks], kf, sc[n0], 0, 0, 0);
      }
    }

    // scale + causal mask + online softmax (wave-parallel row reductions)
    const bool diag = (kb == qt);
    float mnew[4] = {m[0], m[1], m[2], m[3]};
#pragma unroll
    for (int n0 = 0; n0 < 4; ++n0)
#pragma unroll
      for (int j = 0; j < 4; ++j) {
        float v = sc[n0][j] * scale;
        if (diag && ((n0 << 4) + lrow > (wid << 4) + (lk << 2) + j)) v = -1e30f;
        sc[n0][j] = v;
        mnew[j] = fmaxf(mnew[j], v);
      }
#pragma unroll
    for (int j = 0; j < 4; ++j) {
      float v = mnew[j];
      v = fmaxf(v, __shfl_xor(v, 1));
      v = fmaxf(v, __shfl_xor(v, 2));
      v = fmaxf(v, __shfl_xor(v, 4));
      v = fmaxf(v, __shfl_xor(v, 8));
      mnew[j] = v;
    }
    float alpha[4], rs[4] = {0.f, 0.f, 0.f, 0.f};
#pragma unroll
    for (int j = 0; j < 4; ++j) { alpha[j] = __expf(m[j] - mnew[j]); m[j] = mnew[j]; }
#pragma unroll
    for (int n0 = 0; n0 < 4; ++n0)
#pragma unroll
      for (int j = 0; j < 4; ++j) {
        float p = __expf(sc[n0][j] - m[j]);
        sc[n0][j] = p;
        rs[j] += p;
      }
#pragma unroll
    for (int j = 0; j < 4; ++j) {
      float v = rs[j];
      v += __shfl_xor(v, 1); v += __shfl_xor(v, 2);
      v += __shfl_xor(v, 4); v += __shfl_xor(v, 8);
      l[j] = l[j] * alpha[j] + v;
    }
#pragma unroll
    for (int db = 0; db < 8; ++db)
#pragma unroll
      for (int j = 0; j < 4; ++j)
        o[db][j] *= alpha[j];

    // P -> per-wave LDS (pitch 72 elems to break bank conflicts)
    u16* pw = &Ps[wid][0];
#pragma unroll
    for (int n0 = 0; n0 < 4; ++n0)
#pragma unroll
      for (int j = 0; j < 4; ++j)
        pw[((lk << 2) + j) * 72 + (n0 << 4) + lrow] = f2bf(sc[n0][j]);

    // O += P V (16 MFMAs)
#pragma unroll
    for (int t = 0; t < 2; ++t) {
      bf16x8 pf = *(const bf16x8*)(pw + lrow * 72 + (t << 5) + (lk << 3));
#pragma unroll
      for (int db = 0; db < 8; ++db) {
        int dr = (db << 4) + lrow;
        bf16x8 vf = *(const bf16x8*)(Vs + dr * 64 + ((((t << 2) + lk) ^ (dr & 7)) << 3));
        o[db] = __builtin_amdgcn_mfma_f32_16x16x32_bf16(pf, vf, o[db], 0, 0, 0);
      }
    }
    __syncthreads();
  }

#pragma unroll
  for (int j = 0; j < 4; ++j) l[j] = 1.0f / l[j];
  const int qrow0 = (qt << 6) + (wid << 4);
#pragma unroll
  for (int db = 0; db < 8; ++db)
#pragma unroll
    for (int j = 0; j < 4; ++j) {
      int q = qrow0 + (lk << 2) + j;
      ctx[((size_t)(b * S_ + q)) * HD_ + h * D_ + (db << 4) + lrow] = f2bf(o[db][j] * l[j]);
    }
}

extern "C" void kernel_launch(void* const* d_in, const int* in_sizes, int n_in,
                              void* d_out, int out_size, void* d_ws, size_t ws_size,
                              hipStream_t stream) {
  const float* hidden = (const float*)d_in[0];
  const float* Wq = (const float*)d_in[1];
  const float* Wk = (const float*)d_in[2];
  const float* Wv = (const float*)d_in[3];
  const float* Wo = (const float*)d_in[4];
  const int* pos_ids = (const int*)d_in[7];

  char* ws = (char*)d_ws;
  u16* hs    = (u16*)(ws);                    // 32M  hidden bf16
  u16* wqt   = (u16*)(ws + 33554432ull);      // 32M  WqT, later WoT
  u16* wkvt  = (u16*)(ws + 67108864ull);      // 8M   WkT, later WvT
  u16* qlin  = (u16*)(ws + 75497472ull);      // 32M  q_lin, later ctx
  u16* klin  = (u16*)(ws + 109051904ull);     // 8M
  u16* vlin  = (u16*)(ws + 117440512ull);     // 8M
  u16* qr    = (u16*)(ws + 125829120ull);     // 32M  q rope'd [B,H,S,D]
  u16* kr    = (u16*)(ws + 159383552ull);     // 8M   k rope'd [B,KVH,S,D]
  u16* vt    = (u16*)(ws + 167772160ull);     // 8M   v^T [B,KVH,D,S]
  float2* tab = (float2*)(ws + 176160768ull); // 1M   sin/cos table

  // 1. hidden -> bf16
  k_f2bf<<<dim3((M_*E_)/1024), dim3(256), 0, stream>>>(hidden, hs, M_*E_);
  // 2. Wq^T
  k_transpose_f2bf<<<dim3(HD_/32, E_/32), dim3(32, 8), 0, stream>>>(Wq, wqt, E_, HD_);
  // 3. q_lin = hs @ Wq
  k_gemm_bt<false><<<dim3((M_/128)*(HD_/128)), dim3(256), 0, stream>>>(hs, wqt, (void*)qlin, M_, HD_, E_);
  // 4-5. k_lin
  k_transpose_f2bf<<<dim3(KVD_/32, E_/32), dim3(32, 8), 0, stream>>>(Wk, wkvt, E_, KVD_);
  k_gemm_bt<false><<<dim3((M_/128)*(KVD_/128)), dim3(256), 0, stream>>>(hs, wkvt, (void*)klin, M_, KVD_, E_);
  // 6-7. v_lin
  k_transpose_f2bf<<<dim3(KVD_/32, E_/32), dim3(32, 8), 0, stream>>>(Wv, wkvt, E_, KVD_);
  k_gemm_bt<false><<<dim3((M_/128)*(KVD_/128)), dim3(256), 0, stream>>>(hs, wkvt, (void*)vlin, M_, KVD_, E_);
  // 8. Wo^T (reuses wqt buffer; q GEMM done)
  k_transpose_f2bf<<<dim3(E_/32, HD_/32), dim3(32, 8), 0, stream>>>(Wo, wqt, HD_, E_);
  // 9. sin/cos table
  k_table<<<dim3((S_*64)/256), dim3(256), 0, stream>>>(tab);
  // 10-11. RoPE + head reorder
  k_rope<<<dim3((B_*H_*S_*64)/256), dim3(256), 0, stream>>>(qlin, qr, tab, pos_ids, H_, B_*H_*S_*64);
  k_rope<<<dim3((B_*KVH_*S_*64)/256), dim3(256), 0, stream>>>(klin, kr, tab, pos_ids, KVH_, B_*KVH_*S_*64);
  // 12. V transpose -> [B,KVH,D,S]
  k_transpose_v<<<dim3(S_/32, D_/32, B_*KVH_), dim3(32, 8), 0, stream>>>(vlin, vt);
  // 13. flash attention -> ctx (reuses qlin buffer)
  k_attn<<<dim3(B_*H_*(S_/64)), dim3(256), 0, stream>>>(qr, kr, vt, qlin);
  // 14. out = ctx @ Wo (fp32 epilogue)
  k_gemm_bt<true><<<dim3((M_/128)*(E_/128)), dim3(256), 0, stream>>>(qlin, wqt, d_out, M_, E_, HD_);
}